// Round 12
// baseline (236.296 us; speedup 1.0000x reference)
//
#include <hip/hip_runtime.h>
#include <cstdint>
#include <cstddef>

#define NEG_SLOPE 0.2f

typedef __attribute__((ext_vector_type(8))) short short8;
typedef __attribute__((ext_vector_type(4))) float f32x4;

static __device__ __forceinline__ unsigned short f2bf(float x) {
  uint32_t u = __float_as_uint(x);
  uint32_t r = (u + 0x7FFFu + ((u >> 16) & 1u)) >> 16;
  return (unsigned short)r;
}
static __device__ __forceinline__ float bf2f(unsigned short b) {
  return __uint_as_float(((uint32_t)b) << 16);
}

// ---------------------------------------------------------------------------
// W[128][256] f32 -> Wt[256][128] bf16, x3 weight matrices (blockIdx.y).
// ---------------------------------------------------------------------------
__global__ void wt_kernel(const float* __restrict__ W0, const float* __restrict__ W1,
                          const float* __restrict__ W2,
                          unsigned short* __restrict__ T0, unsigned short* __restrict__ T1,
                          unsigned short* __restrict__ T2) {
  const float* W = (blockIdx.y == 0) ? W0 : (blockIdx.y == 1) ? W1 : W2;
  unsigned short* T = (blockIdx.y == 0) ? T0 : (blockIdx.y == 1) ? T1 : T2;
  int c = blockIdx.x * 2 + (threadIdx.x >> 7);   // 0..255
  int k = threadIdx.x & 127;                     // 0..127
  T[c * 128 + k] = f2bf(W[k * 256 + c]);
}

// ---------------------------------------------------------------------------
// MFMA proj, occupancy-first shape: row tile 64 (LDS 16 KB), 4 waves each
// owning a DIFFERENT 64-col quarter. Wt fragments prefetched before staging.
// One barrier. Swapped-operand MFMA => D[ftcol][node]: lane l15 = node,
// regs = 4 consecutive ft cols -> direct ushort4 register stores.
// ---------------------------------------------------------------------------
__global__ __launch_bounds__(256)
void proj_mfma_kernel(const float* __restrict__ fm, const float* __restrict__ fa0,
                      const float* __restrict__ fa1,
                      const unsigned short* __restrict__ Wtm,
                      const unsigned short* __restrict__ Wt0,
                      const unsigned short* __restrict__ Wt1,
                      const float* __restrict__ attn_l, const float* __restrict__ attn_r,
                      int Nm, int Na0, int Na1,
                      unsigned short* __restrict__ ft_all, float* __restrict__ el_all,
                      float* __restrict__ er) {
  const int z = blockIdx.z;
  const float* feats = (z == 0) ? fm : (z == 1) ? fa0 : fa1;
  const unsigned short* Wt = (z == 0) ? Wtm : (z == 1) ? Wt0 : Wt1;
  const float* av = (z == 0) ? attn_r : attn_l;
  const int N = (z == 0) ? Nm : (z == 1) ? Na0 : Na1;
  unsigned short* ft_out = (z == 0) ? nullptr
                         : (z == 1) ? ft_all : ft_all + (size_t)Na0 * 256;
  float* el_out = (z == 0) ? er : (z == 1) ? el_all : el_all + (size_t)Na0 * 8;

  const int rb = blockIdx.x * 64;
  if (rb >= N) return;

  __shared__ unsigned short As[64 * 128];   // 16 KB
  const int t = threadIdx.x;
  const int wid = t >> 6, lane = t & 63;
  const int l15 = lane & 15, l4 = lane >> 4;
  const int cbw = wid * 64;                 // this wave's col quarter
  const int head0 = cbw >> 5;               // 2 heads per wave

  // prefetch Wt fragments (L2-hot, no LDS dependency)
  short8 bf[4][4];                          // [kb][nf]
  #pragma unroll
  for (int nf = 0; nf < 4; ++nf) {
    const unsigned short* wp = &Wt[(size_t)(cbw + nf * 16 + l15) * 128];
    #pragma unroll
    for (int kb = 0; kb < 4; ++kb)
      bf[kb][nf] = *(const short8*)(wp + kb * 32 + l4 * 8);
  }

  // stage feats rows rb..rb+64: f32 -> bf16, swizzled, coalesced
  #pragma unroll
  for (int it = 0; it < 8; ++it) {
    int i = it * 256 + t;
    int r = i >> 5, kc = (i & 31) << 2;
    float4 f = make_float4(0.f, 0.f, 0.f, 0.f);
    if (rb + r < N) f = *(const float4*)(&feats[(size_t)(rb + r) * 128 + kc]);
    ushort4 u;
    u.x = f2bf(f.x); u.y = f2bf(f.y); u.z = f2bf(f.z); u.w = f2bf(f.w);
    uint32_t byte = ((uint32_t)(r * 256 + kc * 2)) ^ ((uint32_t)((r & 7) << 4));
    *(ushort4*)((char*)As + byte) = u;
  }
  __syncthreads();

  f32x4 acc[4][4];                          // [mf][nf]
  #pragma unroll
  for (int a = 0; a < 4; ++a)
    #pragma unroll
    for (int b = 0; b < 4; ++b)
      acc[a][b] = (f32x4){0.f, 0.f, 0.f, 0.f};

  #pragma unroll
  for (int kb = 0; kb < 4; ++kb) {
    short8 af[4];
    #pragma unroll
    for (int mf = 0; mf < 4; ++mf) {
      int row = mf * 16 + l15;
      uint32_t byte = ((uint32_t)(row * 256 + kb * 64 + l4 * 16)) ^ ((uint32_t)((row & 7) << 4));
      af[mf] = *(const short8*)((const char*)As + byte);
    }
    #pragma unroll
    for (int mf = 0; mf < 4; ++mf)
      #pragma unroll
      for (int nf = 0; nf < 4; ++nf)
        acc[mf][nf] = __builtin_amdgcn_mfma_f32_16x16x32_bf16(
            bf[kb][nf], af[mf], acc[mf][nf], 0, 0, 0);
  }

  float avf[4][4];
  #pragma unroll
  for (int nf = 0; nf < 4; ++nf)
    #pragma unroll
    for (int reg = 0; reg < 4; ++reg)
      avf[nf][reg] = av[(head0 + (nf >> 1)) * 32 + (nf & 1) * 16 + l4 * 4 + reg];

  #pragma unroll
  for (int mf = 0; mf < 4; ++mf) {
    int node = rb + mf * 16 + l15;
    bool ok = node < N;
    if (ft_out != nullptr && ok) {
      size_t base = (size_t)node * 256 + cbw + l4 * 4;
      #pragma unroll
      for (int nf = 0; nf < 4; ++nf) {
        ushort4 u;
        u.x = f2bf(acc[mf][nf][0]); u.y = f2bf(acc[mf][nf][1]);
        u.z = f2bf(acc[mf][nf][2]); u.w = f2bf(acc[mf][nf][3]);
        *(ushort4*)(&ft_out[base + nf * 16]) = u;
      }
    }
    #pragma unroll
    for (int hh = 0; hh < 2; ++hh) {
      float p = 0.f;
      #pragma unroll
      for (int reg = 0; reg < 4; ++reg) {
        p = fmaf(acc[mf][2 * hh][reg], avf[2 * hh][reg], p);
        p = fmaf(acc[mf][2 * hh + 1][reg], avf[2 * hh + 1][reg], p);
      }
      p += __shfl_xor(p, 16);
      p += __shfl_xor(p, 32);
      if (ok && l4 == 0)
        el_out[(size_t)node * 8 + head0 + hh] = p;
    }
  }
}

// ---------------------------------------------------------------------------
__global__ void count_deg_kernel(const int* __restrict__ dst0, int E0,
                                 const int* __restrict__ dst1, int E1,
                                 int* __restrict__ deg) {
  int E = E0 + E1;
  for (int i = blockIdx.x * blockDim.x + threadIdx.x; i < E;
       i += gridDim.x * blockDim.x) {
    int d = (i < E0) ? dst0[i] : dst1[i - E0];
    atomicAdd(&deg[d], 1);
  }
}

__global__ __launch_bounds__(1024)
void block_reduce_kernel(const int* __restrict__ deg, int* __restrict__ partial, int n) {
  __shared__ int wsum[16];
  const int t = threadIdx.x;
  int idx = blockIdx.x * 1024 + t;
  int v = (idx < n) ? deg[idx] : 0;
  #pragma unroll
  for (int off = 1; off < 64; off <<= 1) v += __shfl_xor(v, off);
  if ((t & 63) == 0) wsum[t >> 6] = v;
  __syncthreads();
  if (t < 16) {
    int x = wsum[t];
    #pragma unroll
    for (int off = 1; off < 16; off <<= 1) x += __shfl_xor(x, off);
    if (t == 0) partial[blockIdx.x] = x;
  }
}

__global__ __launch_bounds__(64)
void partial_scan_kernel(const int* __restrict__ partial, int* __restrict__ base,
                         int nb, int* __restrict__ offs, int n) {
  const int t = threadIdx.x;
  int v = (t < nb) ? partial[t] : 0;
  int incl = v;
  #pragma unroll
  for (int off = 1; off < 64; off <<= 1) {
    int x = __shfl_up(incl, off);
    if (t >= off) incl += x;
  }
  if (t < nb) base[t] = incl - v;
  if (t == nb - 1) offs[n] = incl;
}

__global__ __launch_bounds__(1024)
void apply_scan_kernel(const int* __restrict__ deg, const int* __restrict__ base,
                       int* __restrict__ offs, int* __restrict__ cursor, int n) {
  __shared__ int wsum[16];
  const int t = threadIdx.x;
  const int idx = blockIdx.x * 1024 + t;
  int v = (idx < n) ? deg[idx] : 0;
  const int lane = t & 63, w = t >> 6;
  int incl = v;
  #pragma unroll
  for (int off = 1; off < 64; off <<= 1) {
    int x = __shfl_up(incl, off);
    if (lane >= off) incl += x;
  }
  if (lane == 63) wsum[w] = incl;
  __syncthreads();
  if (t < 16) {
    int x = wsum[t];
    #pragma unroll
    for (int off = 1; off < 16; off <<= 1) {
      int y = __shfl_up(x, off);
      if (t >= off) x += y;
    }
    wsum[t] = x;
  }
  __syncthreads();
  int excl = base[blockIdx.x] + ((w > 0) ? wsum[w - 1] : 0) + incl - v;
  if (idx < n) {
    offs[idx] = excl;
    cursor[idx] = excl;
  }
}

// ---------------------------------------------------------------------------
// scatter: lightweight -- per edge just {merged src index -> slots[pos]}.
// Weight computation moved into aggregate (el table is L2-hot there).
// ---------------------------------------------------------------------------
__global__ void scatter_kernel(const int* __restrict__ src0, const int* __restrict__ dst0, int E0,
                               const int* __restrict__ src1, const int* __restrict__ dst1, int E1,
                               int* __restrict__ cursor, int* __restrict__ slots, int Na0) {
  int E = E0 + E1;
  for (int i = blockIdx.x * blockDim.x + threadIdx.x; i < E;
       i += gridDim.x * blockDim.x) {
    int s, d;
    if (i < E0) { s = src0[i]; d = dst0[i]; }
    else        { s = src1[i - E0] + Na0; d = dst1[i - E0]; }
    int pos = atomicAdd(&cursor[d], 1);
    slots[pos] = s;
  }
}

// ---------------------------------------------------------------------------
// one wave per dst node. Slot stream is wave-uniform -> readfirstlane pins
// offs/slots loads to the SCALAR path (s_load). Per edge: s_load src -> then
// in PARALLEL {el[s*8+h] gather (3.2 MB L2-hot table, one 32B line/wave),
// ft gather (saddr + loop-invariant lane offset)}. Weight = exp(lrelu(.)) in
// f32 (no bf16 rounding). Single-pass softmax: lrelu logits are O(1)-bounded.
// lane layout: h = lane>>3, d = (lane&7)*4 + j
// ---------------------------------------------------------------------------
__global__ __launch_bounds__(256)
void aggregate_kernel(const int* __restrict__ offs, const int* __restrict__ slots,
                      const float* __restrict__ el, const float* __restrict__ er,
                      const unsigned short* __restrict__ ft,
                      float* __restrict__ rst, int Nm) {
  int gid = blockIdx.x * blockDim.x + threadIdx.x;
  int n = gid >> 6;
  int lane = threadIdx.x & 63;
  if (n >= Nm) return;
  const int nu = __builtin_amdgcn_readfirstlane(n);   // wave-uniform node id
  const int beg = offs[nu], end = offs[nu + 1];       // scalar loads
  const int h = lane >> 3;
  const char* ftl = (const char*)ft + lane * 8;
  const float ern = er[(size_t)nu * 8 + h];           // once per node
  float o0 = 0.f, o1 = 0.f, o2 = 0.f, o3 = 0.f;
  float sw = 0.f;

  #pragma unroll 4
  for (int i = beg; i < end; ++i) {
    int s = slots[i];                                  // s_load (uniform)
    float ev = el[(size_t)(uint32_t)s * 8 + h];        // same-line gather, L2
    uint2 g = *(const uint2*)(ftl + ((size_t)(uint32_t)s << 9));  // ft gather
    float v = ev + ern;
    v = fmaxf(v, NEG_SLOPE * v);                       // leaky relu
    float w = __expf(v);
    sw += w;
    o0 = fmaf(w, __uint_as_float(g.x << 16), o0);
    o1 = fmaf(w, __uint_as_float(g.x & 0xffff0000u), o1);
    o2 = fmaf(w, __uint_as_float(g.y << 16), o2);
    o3 = fmaf(w, __uint_as_float(g.y & 0xffff0000u), o3);
  }

  if (beg < end) {
    float inv = 1.0f / sw;
    o0 *= inv; o1 *= inv; o2 *= inv; o3 *= inv;
  }
  *(float4*)(&rst[(size_t)n * 256 + lane * 4]) = make_float4(o0, o1, o2, o3);
}

// ---------------------------------------------------------------------------
extern "C" void kernel_launch(void* const* d_in, const int* in_sizes, int n_in,
                              void* d_out, int out_size, void* d_ws, size_t ws_size,
                              hipStream_t stream) {
  const float* master = (const float*)d_in[0];
  const float* af0    = (const float*)d_in[1];
  const float* af1    = (const float*)d_in[2];
  const int*   src0   = (const int*)d_in[3];
  const int*   dst0   = (const int*)d_in[4];
  const int*   src1   = (const int*)d_in[5];
  const int*   dst1   = (const int*)d_in[6];
  const float* Wm     = (const float*)d_in[7];
  const float* W0     = (const float*)d_in[8];
  const float* W1     = (const float*)d_in[9];
  const float* attn_l = (const float*)d_in[10];
  const float* attn_r = (const float*)d_in[11];

  const int Nm  = in_sizes[0] / 128;
  const int Na0 = in_sizes[1] / 128;
  const int Na1 = in_sizes[2] / 128;
  const int E0  = in_sizes[3];
  const int E1  = in_sizes[5];
  float* rst = (float*)d_out;

  char* ws = (char*)d_ws;
  size_t off = 0;
  auto alloc = [&](size_t b) -> char* {
    char* p = ws + off;
    off += (b + 511) & ~(size_t)511;
    return p;
  };
  unsigned short* ft = (unsigned short*)alloc((size_t)(Na0 + Na1) * 256 * sizeof(unsigned short));
  float* el = (float*)alloc((size_t)(Na0 + Na1) * 8 * sizeof(float));
  float* er = (float*)alloc((size_t)Nm * 8 * sizeof(float));
  unsigned short* Wtm = (unsigned short*)alloc(256 * 128 * sizeof(unsigned short));
  unsigned short* Wt0 = (unsigned short*)alloc(256 * 128 * sizeof(unsigned short));
  unsigned short* Wt1 = (unsigned short*)alloc(256 * 128 * sizeof(unsigned short));
  int* deg     = (int*)alloc((size_t)Nm * sizeof(int));
  int* offs    = (int*)alloc((size_t)(Nm + 1) * sizeof(int));
  int* cursor  = (int*)alloc((size_t)Nm * sizeof(int));
  int* partial = (int*)alloc(64 * sizeof(int));
  int* pbase   = (int*)alloc(64 * sizeof(int));
  int* slots   = (int*)alloc((size_t)(E0 + E1) * sizeof(int));

  wt_kernel<<<dim3(128, 3), 256, 0, stream>>>(Wm, W0, W1, Wtm, Wt0, Wt1);

  int Nmax = Nm > Na0 ? Nm : Na0; if (Na1 > Nmax) Nmax = Na1;
  const int mb = (Nmax + 63) / 64;
  proj_mfma_kernel<<<dim3(mb, 1, 3), 256, 0, stream>>>(
      master, af0, af1, Wtm, Wt0, Wt1, attn_l, attn_r,
      Nm, Na0, Na1, ft, el, er);

  hipMemsetAsync(deg, 0, (size_t)Nm * sizeof(int), stream);
  count_deg_kernel<<<1024, 256, 0, stream>>>(dst0, E0, dst1, E1, deg);
  const int nb = (Nm + 1023) / 1024;   // <= 64
  block_reduce_kernel<<<nb, 1024, 0, stream>>>(deg, partial, Nm);
  partial_scan_kernel<<<1, 64, 0, stream>>>(partial, pbase, nb, offs, Nm);
  apply_scan_kernel<<<nb, 1024, 0, stream>>>(deg, pbase, offs, cursor, Nm);
  scatter_kernel<<<1024, 256, 0, stream>>>(src0, dst0, E0, src1, dst1, E1,
                                           cursor, slots, Na0);

  aggregate_kernel<<<(Nm + 3) / 4, 256, 0, stream>>>(offs, slots, el, er, ft, rst, Nm);
}

// Round 13
// 205.903 us; speedup vs baseline: 1.1476x; 1.1476x over previous
//
#include <hip/hip_runtime.h>
#include <cstdint>
#include <cstddef>

#define NEG_SLOPE 0.2f

typedef __attribute__((ext_vector_type(8))) short short8;
typedef __attribute__((ext_vector_type(4))) float f32x4;

static __device__ __forceinline__ unsigned short f2bf(float x) {
  uint32_t u = __float_as_uint(x);
  uint32_t r = (u + 0x7FFFu + ((u >> 16) & 1u)) >> 16;
  return (unsigned short)r;
}
static __device__ __forceinline__ float bf2f(unsigned short b) {
  return __uint_as_float(((uint32_t)b) << 16);
}

// ---------------------------------------------------------------------------
// W[128][256] f32 -> Wt[256][128] bf16, x3 weight matrices (blockIdx.y).
// ---------------------------------------------------------------------------
__global__ void wt_kernel(const float* __restrict__ W0, const float* __restrict__ W1,
                          const float* __restrict__ W2,
                          unsigned short* __restrict__ T0, unsigned short* __restrict__ T1,
                          unsigned short* __restrict__ T2) {
  const float* W = (blockIdx.y == 0) ? W0 : (blockIdx.y == 1) ? W1 : W2;
  unsigned short* T = (blockIdx.y == 0) ? T0 : (blockIdx.y == 1) ? T1 : T2;
  int c = blockIdx.x * 2 + (threadIdx.x >> 7);   // 0..255
  int k = threadIdx.x & 127;                     // 0..127
  T[c * 128 + k] = f2bf(W[k * 256 + c]);
}

// ---------------------------------------------------------------------------
// MFMA proj, occupancy-first shape: row tile 64 (LDS 16 KB), 4 waves each
// owning a DIFFERENT 64-col quarter. Wt fragments prefetched before staging.
// One barrier. Swapped-operand MFMA => D[ftcol][node]: lane l15 = node,
// regs = 4 consecutive ft cols -> direct ushort4 register stores.
// ---------------------------------------------------------------------------
__global__ __launch_bounds__(256)
void proj_mfma_kernel(const float* __restrict__ fm, const float* __restrict__ fa0,
                      const float* __restrict__ fa1,
                      const unsigned short* __restrict__ Wtm,
                      const unsigned short* __restrict__ Wt0,
                      const unsigned short* __restrict__ Wt1,
                      const float* __restrict__ attn_l, const float* __restrict__ attn_r,
                      int Nm, int Na0, int Na1,
                      unsigned short* __restrict__ ft_all, float* __restrict__ el_all,
                      float* __restrict__ er) {
  const int z = blockIdx.z;
  const float* feats = (z == 0) ? fm : (z == 1) ? fa0 : fa1;
  const unsigned short* Wt = (z == 0) ? Wtm : (z == 1) ? Wt0 : Wt1;
  const float* av = (z == 0) ? attn_r : attn_l;
  const int N = (z == 0) ? Nm : (z == 1) ? Na0 : Na1;
  unsigned short* ft_out = (z == 0) ? nullptr
                         : (z == 1) ? ft_all : ft_all + (size_t)Na0 * 256;
  float* el_out = (z == 0) ? er : (z == 1) ? el_all : el_all + (size_t)Na0 * 8;

  const int rb = blockIdx.x * 64;
  if (rb >= N) return;

  __shared__ unsigned short As[64 * 128];   // 16 KB
  const int t = threadIdx.x;
  const int wid = t >> 6, lane = t & 63;
  const int l15 = lane & 15, l4 = lane >> 4;
  const int cbw = wid * 64;                 // this wave's col quarter
  const int head0 = cbw >> 5;               // 2 heads per wave

  // prefetch Wt fragments (L2-hot, no LDS dependency)
  short8 bf[4][4];                          // [kb][nf]
  #pragma unroll
  for (int nf = 0; nf < 4; ++nf) {
    const unsigned short* wp = &Wt[(size_t)(cbw + nf * 16 + l15) * 128];
    #pragma unroll
    for (int kb = 0; kb < 4; ++kb)
      bf[kb][nf] = *(const short8*)(wp + kb * 32 + l4 * 8);
  }

  // stage feats rows rb..rb+64: f32 -> bf16, swizzled, coalesced
  #pragma unroll
  for (int it = 0; it < 8; ++it) {
    int i = it * 256 + t;
    int r = i >> 5, kc = (i & 31) << 2;
    float4 f = make_float4(0.f, 0.f, 0.f, 0.f);
    if (rb + r < N) f = *(const float4*)(&feats[(size_t)(rb + r) * 128 + kc]);
    ushort4 u;
    u.x = f2bf(f.x); u.y = f2bf(f.y); u.z = f2bf(f.z); u.w = f2bf(f.w);
    uint32_t byte = ((uint32_t)(r * 256 + kc * 2)) ^ ((uint32_t)((r & 7) << 4));
    *(ushort4*)((char*)As + byte) = u;
  }
  __syncthreads();

  f32x4 acc[4][4];                          // [mf][nf]
  #pragma unroll
  for (int a = 0; a < 4; ++a)
    #pragma unroll
    for (int b = 0; b < 4; ++b)
      acc[a][b] = (f32x4){0.f, 0.f, 0.f, 0.f};

  #pragma unroll
  for (int kb = 0; kb < 4; ++kb) {
    short8 af[4];
    #pragma unroll
    for (int mf = 0; mf < 4; ++mf) {
      int row = mf * 16 + l15;
      uint32_t byte = ((uint32_t)(row * 256 + kb * 64 + l4 * 16)) ^ ((uint32_t)((row & 7) << 4));
      af[mf] = *(const short8*)((const char*)As + byte);
    }
    #pragma unroll
    for (int mf = 0; mf < 4; ++mf)
      #pragma unroll
      for (int nf = 0; nf < 4; ++nf)
        acc[mf][nf] = __builtin_amdgcn_mfma_f32_16x16x32_bf16(
            bf[kb][nf], af[mf], acc[mf][nf], 0, 0, 0);
  }

  float avf[4][4];
  #pragma unroll
  for (int nf = 0; nf < 4; ++nf)
    #pragma unroll
    for (int reg = 0; reg < 4; ++reg)
      avf[nf][reg] = av[(head0 + (nf >> 1)) * 32 + (nf & 1) * 16 + l4 * 4 + reg];

  #pragma unroll
  for (int mf = 0; mf < 4; ++mf) {
    int node = rb + mf * 16 + l15;
    bool ok = node < N;
    if (ft_out != nullptr && ok) {
      size_t base = (size_t)node * 256 + cbw + l4 * 4;
      #pragma unroll
      for (int nf = 0; nf < 4; ++nf) {
        ushort4 u;
        u.x = f2bf(acc[mf][nf][0]); u.y = f2bf(acc[mf][nf][1]);
        u.z = f2bf(acc[mf][nf][2]); u.w = f2bf(acc[mf][nf][3]);
        *(ushort4*)(&ft_out[base + nf * 16]) = u;
      }
    }
    #pragma unroll
    for (int hh = 0; hh < 2; ++hh) {
      float p = 0.f;
      #pragma unroll
      for (int reg = 0; reg < 4; ++reg) {
        p = fmaf(acc[mf][2 * hh][reg], avf[2 * hh][reg], p);
        p = fmaf(acc[mf][2 * hh + 1][reg], avf[2 * hh + 1][reg], p);
      }
      p += __shfl_xor(p, 16);
      p += __shfl_xor(p, 32);
      if (ok && l4 == 0)
        el_out[(size_t)node * 8 + head0 + hh] = p;
    }
  }
}

// ---------------------------------------------------------------------------
__global__ void count_deg_kernel(const int* __restrict__ dst0, int E0,
                                 const int* __restrict__ dst1, int E1,
                                 int* __restrict__ deg) {
  int E = E0 + E1;
  for (int i = blockIdx.x * blockDim.x + threadIdx.x; i < E;
       i += gridDim.x * blockDim.x) {
    int d = (i < E0) ? dst0[i] : dst1[i - E0];
    atomicAdd(&deg[d], 1);
  }
}

__global__ __launch_bounds__(1024)
void block_reduce_kernel(const int* __restrict__ deg, int* __restrict__ partial, int n) {
  __shared__ int wsum[16];
  const int t = threadIdx.x;
  int idx = blockIdx.x * 1024 + t;
  int v = (idx < n) ? deg[idx] : 0;
  #pragma unroll
  for (int off = 1; off < 64; off <<= 1) v += __shfl_xor(v, off);
  if ((t & 63) == 0) wsum[t >> 6] = v;
  __syncthreads();
  if (t < 16) {
    int x = wsum[t];
    #pragma unroll
    for (int off = 1; off < 16; off <<= 1) x += __shfl_xor(x, off);
    if (t == 0) partial[blockIdx.x] = x;
  }
}

__global__ __launch_bounds__(64)
void partial_scan_kernel(const int* __restrict__ partial, int* __restrict__ base,
                         int nb, int* __restrict__ offs, int n) {
  const int t = threadIdx.x;
  int v = (t < nb) ? partial[t] : 0;
  int incl = v;
  #pragma unroll
  for (int off = 1; off < 64; off <<= 1) {
    int x = __shfl_up(incl, off);
    if (t >= off) incl += x;
  }
  if (t < nb) base[t] = incl - v;
  if (t == nb - 1) offs[n] = incl;
}

__global__ __launch_bounds__(1024)
void apply_scan_kernel(const int* __restrict__ deg, const int* __restrict__ base,
                       int* __restrict__ offs, int* __restrict__ cursor, int n) {
  __shared__ int wsum[16];
  const int t = threadIdx.x;
  const int idx = blockIdx.x * 1024 + t;
  int v = (idx < n) ? deg[idx] : 0;
  const int lane = t & 63, w = t >> 6;
  int incl = v;
  #pragma unroll
  for (int off = 1; off < 64; off <<= 1) {
    int x = __shfl_up(incl, off);
    if (lane >= off) incl += x;
  }
  if (lane == 63) wsum[w] = incl;
  __syncthreads();
  if (t < 16) {
    int x = wsum[t];
    #pragma unroll
    for (int off = 1; off < 16; off <<= 1) {
      int y = __shfl_up(x, off);
      if (t >= off) x += y;
    }
    wsum[t] = x;
  }
  __syncthreads();
  int excl = base[blockIdx.x] + ((w > 0) ? wsum[w - 1] : 0) + incl - v;
  if (idx < n) {
    offs[idx] = excl;
    cursor[idx] = excl;
  }
}

// ---------------------------------------------------------------------------
// scatter: per edge, one 32-byte-aligned record {src, w[8] bf16} (20 B used)
// at the CSR slot. Weights are exp(lrelu(el[src]+er[dst])) -- single-pass
// softmax, O(1)-bounded logits.
// ---------------------------------------------------------------------------
__global__ void scatter_kernel(const int* __restrict__ src0, const int* __restrict__ dst0, int E0,
                               const int* __restrict__ src1, const int* __restrict__ dst1, int E1,
                               int* __restrict__ cursor, char* __restrict__ recs,
                               const float* __restrict__ el, const float* __restrict__ er,
                               int Na0) {
  int E = E0 + E1;
  for (int i = blockIdx.x * blockDim.x + threadIdx.x; i < E;
       i += gridDim.x * blockDim.x) {
    int s, d;
    if (i < E0) { s = src0[i]; d = dst0[i]; }
    else        { s = src1[i - E0] + Na0; d = dst1[i - E0]; }
    int pos = atomicAdd(&cursor[d], 1);

    const float* elp = &el[(size_t)s * 8];
    const float* erp = &er[(size_t)d * 8];
    float4 ea = *(const float4*)elp, eb = *(const float4*)(elp + 4);
    float4 ra = *(const float4*)erp, rb = *(const float4*)(erp + 4);
    float w[8];
    w[0] = ea.x + ra.x; w[1] = ea.y + ra.y; w[2] = ea.z + ra.z; w[3] = ea.w + ra.w;
    w[4] = eb.x + rb.x; w[5] = eb.y + rb.y; w[6] = eb.z + rb.z; w[7] = eb.w + rb.w;
    uint32_t pk[4];
    #pragma unroll
    for (int q = 0; q < 4; ++q) {
      float v0 = w[2 * q], v1 = w[2 * q + 1];
      v0 = fmaxf(v0, NEG_SLOPE * v0);
      v1 = fmaxf(v1, NEG_SLOPE * v1);
      uint32_t b0 = f2bf(__expf(v0)), b1 = f2bf(__expf(v1));
      pk[q] = b0 | (b1 << 16);
    }
    char* rp = recs + ((size_t)(uint32_t)pos << 5);
    *(uint4*)rp = make_uint4((uint32_t)s, pk[0], pk[1], pk[2]);
    *(uint32_t*)(rp + 16) = pk[3];
  }
}

// ---------------------------------------------------------------------------
// one wave per dst node. Records are wave-uniform -> readfirstlane pins the
// record/offs loads to the SCALAR path (s_load, no VMEM, no VGPR addressing);
// src lands in an SGPR so the ft gather is saddr + loop-invariant lane offset.
// Weight picked from 4 SGPRs by 3 cndmask (loop-invariant masks) + shift.
// unroll 8: eight records' s_loads + eight independent ft gathers per group.
// lane layout: h = lane>>3, d = (lane&7)*4 + j
// ---------------------------------------------------------------------------
__global__ __launch_bounds__(256)
void aggregate_kernel(const int* __restrict__ offs, const char* __restrict__ recs,
                      const unsigned short* __restrict__ ft,
                      float* __restrict__ rst, int Nm) {
  int gid = blockIdx.x * blockDim.x + threadIdx.x;
  int n = gid >> 6;
  int lane = threadIdx.x & 63;
  if (n >= Nm) return;
  const int nu = __builtin_amdgcn_readfirstlane(n);   // wave-uniform node id
  const int beg = offs[nu], end = offs[nu + 1];       // scalar loads
  const int h = lane >> 3;
  const char* ftl = (const char*)ft + lane * 8;
  float o0 = 0.f, o1 = 0.f, o2 = 0.f, o3 = 0.f;
  float sw = 0.f;

  #pragma unroll 8
  for (int i = beg; i < end; ++i) {
    const uint32_t* rp = (const uint32_t*)(recs + ((size_t)(uint32_t)i << 5));
    uint32_t sct = rp[0];                         // SGPR: src index
    uint32_t d0 = rp[1], d1 = rp[2], d2 = rp[3], d3 = rp[4];   // SGPR: weights
    uint2 g = *(const uint2*)(ftl + ((size_t)sct << 9));        // the only gather
    uint32_t wa = (h & 2) ? d1 : d0;
    uint32_t wb = (h & 2) ? d3 : d2;
    uint32_t wsl = (h & 4) ? wb : wa;
    float w = __uint_as_float((h & 1) ? (wsl & 0xffff0000u) : (wsl << 16));
    sw += w;
    o0 = fmaf(w, __uint_as_float(g.x << 16), o0);
    o1 = fmaf(w, __uint_as_float(g.x & 0xffff0000u), o1);
    o2 = fmaf(w, __uint_as_float(g.y << 16), o2);
    o3 = fmaf(w, __uint_as_float(g.y & 0xffff0000u), o3);
  }

  if (beg < end) {
    float inv = 1.0f / sw;
    o0 *= inv; o1 *= inv; o2 *= inv; o3 *= inv;
  }
  *(float4*)(&rst[(size_t)n * 256 + lane * 4]) = make_float4(o0, o1, o2, o3);
}

// ---------------------------------------------------------------------------
extern "C" void kernel_launch(void* const* d_in, const int* in_sizes, int n_in,
                              void* d_out, int out_size, void* d_ws, size_t ws_size,
                              hipStream_t stream) {
  const float* master = (const float*)d_in[0];
  const float* af0    = (const float*)d_in[1];
  const float* af1    = (const float*)d_in[2];
  const int*   src0   = (const int*)d_in[3];
  const int*   dst0   = (const int*)d_in[4];
  const int*   src1   = (const int*)d_in[5];
  const int*   dst1   = (const int*)d_in[6];
  const float* Wm     = (const float*)d_in[7];
  const float* W0     = (const float*)d_in[8];
  const float* W1     = (const float*)d_in[9];
  const float* attn_l = (const float*)d_in[10];
  const float* attn_r = (const float*)d_in[11];

  const int Nm  = in_sizes[0] / 128;
  const int Na0 = in_sizes[1] / 128;
  const int Na1 = in_sizes[2] / 128;
  const int E0  = in_sizes[3];
  const int E1  = in_sizes[5];
  float* rst = (float*)d_out;

  char* ws = (char*)d_ws;
  size_t off = 0;
  auto alloc = [&](size_t b) -> char* {
    char* p = ws + off;
    off += (b + 511) & ~(size_t)511;
    return p;
  };
  unsigned short* ft = (unsigned short*)alloc((size_t)(Na0 + Na1) * 256 * sizeof(unsigned short));
  float* el = (float*)alloc((size_t)(Na0 + Na1) * 8 * sizeof(float));
  float* er = (float*)alloc((size_t)Nm * 8 * sizeof(float));
  unsigned short* Wtm = (unsigned short*)alloc(256 * 128 * sizeof(unsigned short));
  unsigned short* Wt0 = (unsigned short*)alloc(256 * 128 * sizeof(unsigned short));
  unsigned short* Wt1 = (unsigned short*)alloc(256 * 128 * sizeof(unsigned short));
  int* deg     = (int*)alloc((size_t)Nm * sizeof(int));
  int* offs    = (int*)alloc((size_t)(Nm + 1) * sizeof(int));
  int* cursor  = (int*)alloc((size_t)Nm * sizeof(int));
  int* partial = (int*)alloc(64 * sizeof(int));
  int* pbase   = (int*)alloc(64 * sizeof(int));
  char* recs   = alloc((size_t)(E0 + E1) * 32);

  wt_kernel<<<dim3(128, 3), 256, 0, stream>>>(Wm, W0, W1, Wtm, Wt0, Wt1);

  int Nmax = Nm > Na0 ? Nm : Na0; if (Na1 > Nmax) Nmax = Na1;
  const int mb = (Nmax + 63) / 64;
  proj_mfma_kernel<<<dim3(mb, 1, 3), 256, 0, stream>>>(
      master, af0, af1, Wtm, Wt0, Wt1, attn_l, attn_r,
      Nm, Na0, Na1, ft, el, er);

  hipMemsetAsync(deg, 0, (size_t)Nm * sizeof(int), stream);
  const int E = E0 + E1;
  const int eb = (E + 255) / 256;      // one edge per thread
  count_deg_kernel<<<eb, 256, 0, stream>>>(dst0, E0, dst1, E1, deg);
  const int nb = (Nm + 1023) / 1024;   // <= 64
  block_reduce_kernel<<<nb, 1024, 0, stream>>>(deg, partial, Nm);
  partial_scan_kernel<<<1, 64, 0, stream>>>(partial, pbase, nb, offs, Nm);
  apply_scan_kernel<<<nb, 1024, 0, stream>>>(deg, pbase, offs, cursor, Nm);
  scatter_kernel<<<eb, 256, 0, stream>>>(src0, dst0, E0, src1, dst1, E1,
                                         cursor, recs, el, er, Na0);

  aggregate_kernel<<<(Nm + 3) / 4, 256, 0, stream>>>(offs, recs, ft, rst, Nm);
}